// Round 1
// baseline (319.769 us; speedup 1.0000x reference)
//
#include <hip/hip_runtime.h>
#include <cmath>

#define Bb 4
#define Ll 2048
#define Dd 1024
#define Hh 64
// M = Bb*Ll = 8192 rows

// ---------------- Kernel 1: q = x @ Wq^T  (fp32, LDS-tiled) ----------------
// grid 256 blocks (BM=32 rows each), block 256 threads (4 waves).
// Per K-chunk of 64: stage x[32][64] and Wq packed-transposed [dg][h] (float4 over d).
__global__ __launch_bounds__(256) void proj_kernel(const float* __restrict__ x,
                                                   const float* __restrict__ Wq,
                                                   float* __restrict__ q) {
    __shared__ float4 xs[32 * 17];   // x[row][dg], row stride 17 f4 (68 floats)
    __shared__ float4 ws[16 * 65];   // Wq4T[dg][h], dg stride 65 f4 (conflict-free writes+reads)
    const int t    = threadIdx.x;
    const int lane = t & 63;         // h
    const int wv   = t >> 6;         // wave 0..3 -> rows wv*8..wv*8+7
    const int row0 = blockIdx.x * 32;

    float acc[8];
#pragma unroll
    for (int r = 0; r < 8; ++r) acc[r] = 0.f;

    for (int d0 = 0; d0 < Dd; d0 += 64) {
        __syncthreads();
        // stage x: 32 rows x 16 f4 = 512 f4, 2 per thread
#pragma unroll
        for (int k = 0; k < 2; ++k) {
            int idx = t + k * 256;
            int r = idx >> 4, dg = idx & 15;
            xs[r * 17 + dg] = *(const float4*)(&x[(size_t)(row0 + r) * Dd + d0 + dg * 4]);
        }
        // stage Wq transposed-packed: 64 h x 16 f4 = 1024 f4, 4 per thread
#pragma unroll
        for (int k = 0; k < 4; ++k) {
            int idx = t + k * 256;
            int h = idx >> 4, dg = idx & 15;
            ws[dg * 65 + h] = *(const float4*)(&Wq[(size_t)h * Dd + d0 + dg * 4]);
        }
        __syncthreads();
        const int rb = wv * 8;
#pragma unroll
        for (int dg = 0; dg < 16; ++dg) {
            float4 w4 = ws[dg * 65 + lane];          // lanes consecutive -> conflict-free
#pragma unroll
            for (int r = 0; r < 8; ++r) {
                float4 x4 = xs[(rb + r) * 17 + dg];  // wave-uniform broadcast
                acc[r] += x4.x * w4.x + x4.y * w4.y + x4.z * w4.z + x4.w * w4.w;
            }
        }
    }
#pragma unroll
    for (int r = 0; r < 8; ++r)
        q[(size_t)(row0 + wv * 8 + r) * Hh + lane] = acc[r];
}

// ---------------- Kernel 2: causal flash attention, k=v=q ----------------
// grid (64, B): block handles Q-tiles qt and 127-qt (BM=16) -> uniform work.
// block 256 threads = 4 waves; wave w owns rows 4w..4w+3, lane = col / h index.
__global__ __launch_bounds__(256) void flash_kernel(const float* __restrict__ q,
                                                    float* __restrict__ out) {
    __shared__ float4 Qs[16 * 17];   // Q[r][dg], pre-scaled by 1/32
    __shared__ float4 Ks[64 * 17];   // K(=V) tile [c][dg], row stride 68 floats
    __shared__ float4 Ps[16 * 17];   // P[r][kg]
    const int t    = threadIdx.x;
    const int lane = t & 63;
    const int w    = t >> 6;
    const int b    = blockIdx.y;
    const float* qb = q + (size_t)b * Ll * Hh;
    float* ob       = out + (size_t)b * Ll * Hh;
    float* Psf      = (float*)Ps;
    const float* Ksf = (const float*)Ks;

    for (int phase = 0; phase < 2; ++phase) {
        const int qt = (phase == 0) ? (int)blockIdx.x : (127 - (int)blockIdx.x);
        const int r0 = qt * 16;
        __syncthreads();   // previous phase's readers of Qs/Ks are done
        {   // load+scale Q tile: 16 rows x 16 f4, 1 per thread
            int r = t >> 4, dg = t & 15;
            float4 v = *(const float4*)(&qb[(size_t)(r0 + r) * Hh + dg * 4]);
            v.x *= 0.03125f; v.y *= 0.03125f; v.z *= 0.03125f; v.w *= 0.03125f;
            Qs[r * 17 + dg] = v;
        }
        float m[4], l[4], o[4];
#pragma unroll
        for (int i = 0; i < 4; ++i) { m[i] = -INFINITY; l[i] = 0.f; o[i] = 0.f; }

        const int ntiles = qt / 4 + 1;           // KV tiles of 64 cols, causal
        for (int j = 0; j < ntiles; ++j) {
            const int c0 = j * 64;
            __syncthreads();
            // stage K tile: 64 rows x 16 f4 = 1024 f4, 4 per thread
#pragma unroll
            for (int k = 0; k < 4; ++k) {
                int idx = t + k * 256;
                int c = idx >> 4, dg = idx & 15;
                Ks[c * 17 + dg] = *(const float4*)(&qb[(size_t)(c0 + c) * Hh + dg * 4]);
            }
            __syncthreads();
            // S = Qs . Ks^T   (Q pre-scaled)
            float s[4];
#pragma unroll
            for (int rq = 0; rq < 4; ++rq) s[rq] = 0.f;
#pragma unroll
            for (int dg = 0; dg < 16; ++dg) {
                float4 k4 = Ks[lane * 17 + dg];              // conflict-free (stride 17 f4)
#pragma unroll
                for (int rq = 0; rq < 4; ++rq) {
                    float4 q4 = Qs[(w * 4 + rq) * 17 + dg];  // broadcast
                    s[rq] += q4.x * k4.x + q4.y * k4.y + q4.z * k4.z + q4.w * k4.w;
                }
            }
            const int col = c0 + lane;
            // online softmax per row (row is wholly inside one wave)
#pragma unroll
            for (int rq = 0; rq < 4; ++rq) {
                const int row = r0 + w * 4 + rq;
                float sv = (col <= row) ? s[rq] : -INFINITY;
                float tmax = sv;
#pragma unroll
                for (int off = 32; off >= 1; off >>= 1)
                    tmax = fmaxf(tmax, __shfl_xor(tmax, off, 64));
                float mnew = fmaxf(m[rq], tmax);             // finite: c0 <= row always
                float p = __expf(sv - mnew);                 // -inf -> 0
                float alpha = __expf(m[rq] - mnew);          // first iter: exp(-inf)=0
                float psum = p;
#pragma unroll
                for (int off = 32; off >= 1; off >>= 1)
                    psum += __shfl_xor(psum, off, 64);
                l[rq] = l[rq] * alpha + psum;
                o[rq] *= alpha;
                m[rq] = mnew;
                Psf[(w * 4 + rq) * 68 + lane] = p;           // own wave only -> no barrier
            }
            // O += P @ V  (V = K tile)
#pragma unroll
            for (int kg = 0; kg < 16; ++kg) {
                float v0 = Ksf[(kg * 4 + 0) * 68 + lane];
                float v1 = Ksf[(kg * 4 + 1) * 68 + lane];
                float v2 = Ksf[(kg * 4 + 2) * 68 + lane];
                float v3 = Ksf[(kg * 4 + 3) * 68 + lane];
#pragma unroll
                for (int rq = 0; rq < 4; ++rq) {
                    float4 p4 = Ps[(w * 4 + rq) * 17 + kg];  // broadcast
                    o[rq] += p4.x * v0 + p4.y * v1 + p4.z * v2 + p4.w * v3;
                }
            }
        }
#pragma unroll
        for (int rq = 0; rq < 4; ++rq)
            ob[(size_t)(r0 + w * 4 + rq) * Hh + lane] = o[rq] / l[rq];
    }
}

extern "C" void kernel_launch(void* const* d_in, const int* in_sizes, int n_in,
                              void* d_out, int out_size, void* d_ws, size_t ws_size,
                              hipStream_t stream) {
    const float* x  = (const float*)d_in[0];   // [4,2048,1024]
    const float* Wq = (const float*)d_in[1];   // [64,1024]
    float* out = (float*)d_out;                // [4,2048,64]
    float* q   = (float*)d_ws;                 // 8192*64 fp32 = 2 MB scratch

    proj_kernel<<<256, 256, 0, stream>>>(x, Wq, q);
    flash_kernel<<<dim3(64, Bb), 256, 0, stream>>>(q, out);
}

// Round 2
// 118.694 us; speedup vs baseline: 2.6941x; 2.6941x over previous
//
#include <hip/hip_runtime.h>
#include <cmath>

#define Bb 4
#define Ll 2048
#define Dd 1024
#define Hh 64

typedef float f32x4 __attribute__((ext_vector_type(4)));
typedef short s16x8 __attribute__((ext_vector_type(8)));

__device__ __forceinline__ unsigned short f2bf(float f) {
    union { float f; unsigned int u; } v; v.f = f;
    unsigned int u = v.u;
    return (unsigned short)((u + 0x7FFFu + ((u >> 16) & 1u)) >> 16);  // RNE
}
__device__ __forceinline__ unsigned int pack2(float a, float b) {
    return (unsigned int)f2bf(a) | ((unsigned int)f2bf(b) << 16);
}

// ---------------- Kernel 1: q = x @ Wq^T, bf16 MFMA, emits q and qT ----------------
// grid 512 (16 rows each), 256 threads. BK=128. XOR-swizzled LDS: 2-way conflicts only.
// C layout (16x16x32): col=lane&15, row=(lane>>4)*4+reg.  A/B frag: [m|n=lane&15][k=quad*8+j].
__global__ __launch_bounds__(256) void proj_mfma(const float* __restrict__ x,
                                                 const float* __restrict__ Wq,
                                                 unsigned short* __restrict__ q,
                                                 unsigned short* __restrict__ qT) {
    __shared__ uint4 xs4[16 * 16];   // slot = kc*16 + (r ^ kc)   (16 B chunks of 8 bf16)
    __shared__ uint4 ws4[16 * 64];   // slot = kc*64 + (h ^ kc)
    const int t = threadIdx.x;
    const int lane = t & 63;
    const int w = t >> 6;
    const int m15 = lane & 15;
    const int q_ = lane >> 4;
    const int row0 = blockIdx.x * 16;

    f32x4 acc = {0.f, 0.f, 0.f, 0.f};
    const int rx = t >> 4, kcx = t & 15;

    for (int k0 = 0; k0 < Dd; k0 += 128) {
        __syncthreads();
        {   // stage x[16][128] -> bf16 (coalesced 32 B/thread)
            const float* src = x + (size_t)(row0 + rx) * Dd + k0 + kcx * 8;
            float4 a = *(const float4*)src;
            float4 b = *(const float4*)(src + 4);
            uint4 p; p.x = pack2(a.x, a.y); p.y = pack2(a.z, a.w);
            p.z = pack2(b.x, b.y); p.w = pack2(b.z, b.w);
            xs4[kcx * 16 + (rx ^ kcx)] = p;
        }
#pragma unroll
        for (int j = 0; j < 4; ++j) {   // stage Wq[64][128] -> bf16
            int idx = t + j * 256;
            int h = idx >> 4, kc = idx & 15;
            const float* src = Wq + (size_t)h * Dd + k0 + kc * 8;
            float4 a = *(const float4*)src;
            float4 b = *(const float4*)(src + 4);
            uint4 p; p.x = pack2(a.x, a.y); p.y = pack2(a.z, a.w);
            p.z = pack2(b.x, b.y); p.w = pack2(b.z, b.w);
            ws4[kc * 64 + (h ^ kc)] = p;
        }
        __syncthreads();
        const int hB = w * 16 + m15;
#pragma unroll
        for (int ks = 0; ks < 4; ++ks) {
            int kc = ks * 4 + q_;
            s16x8 A = *(const s16x8*)&xs4[kc * 16 + (m15 ^ kc)];
            s16x8 B = *(const s16x8*)&ws4[kc * 64 + (hB ^ kc)];
            acc = __builtin_amdgcn_mfma_f32_16x16x32_bf16(A, B, acc, 0, 0, 0);
        }
    }
    const int h = w * 16 + m15;            // C col
    const int b = row0 >> 11;
    const int mloc = (row0 & 2047) + q_ * 4;
    unsigned short u0 = f2bf(acc[0]), u1 = f2bf(acc[1]), u2 = f2bf(acc[2]), u3 = f2bf(acc[3]);
    q[(size_t)(row0 + q_ * 4 + 0) * Hh + h] = u0;
    q[(size_t)(row0 + q_ * 4 + 1) * Hh + h] = u1;
    q[(size_t)(row0 + q_ * 4 + 2) * Hh + h] = u2;
    q[(size_t)(row0 + q_ * 4 + 3) * Hh + h] = u3;
    ushort4 pk; pk.x = u0; pk.y = u1; pk.z = u2; pk.w = u3;   // 4 consecutive seq positions
    *(ushort4*)&qT[((size_t)(b * Hh + h)) * Ll + mloc] = pk;
}

// ---------------- Kernel 2: split-KV MFMA flash; k=v=q ----------------
// grid (qt=32, slice=8, b=4); block 256 = 4 waves; wave w owns rows w*16..w*16+15 of
// the 64-row q-tile. Slice = 256 keys = up to 4 BN=64 iterations.
// Writes unnormalized O partial + (m,l) per row to workspace.
__global__ __launch_bounds__(256) void flash_mfma(const unsigned short* __restrict__ qg,
                                                  const unsigned short* __restrict__ qTg,
                                                  float* __restrict__ PO,
                                                  float* __restrict__ ML) {
    const int qt = blockIdx.x;
    const int s  = blockIdx.y;
    const int b  = blockIdx.z;
    if (s > (qt >> 2)) return;                       // causal: slice beyond diagonal
    __shared__ uint4 Qs4[512], Ks4[512], Vt4[512];   // [hc|cc][r|c|h] swizzled, 8 KB each
    __shared__ __align__(16) unsigned short Pb[4 * 128 * 8];  // per-wave P, A-frag layout
    const int t = threadIdx.x, lane = t & 63, w = t >> 6;
    const int m15 = lane & 15, q_ = lane >> 4;
    const unsigned short* qb  = qg  + (size_t)b * Ll * Hh;
    const unsigned short* qTb = qTg + (size_t)b * Hh * Ll;

#pragma unroll
    for (int j = 0; j < 2; ++j) {   // stage Q tile (rows qt*64..+63)
        int idx = t + j * 256;
        int r = idx >> 3, hc = idx & 7;
        Qs4[hc * 64 + (r ^ hc)] = *(const uint4*)(qb + (size_t)(qt * 64 + r) * Hh + hc * 8);
    }
    f32x4 Oacc[4];
    float mr[4], lr[4];
#pragma unroll
    for (int i = 0; i < 4; ++i) {
        Oacc[i] = (f32x4){0.f, 0.f, 0.f, 0.f};
        mr[i] = -INFINITY; lr[i] = 0.f;
    }
    const int n_it = min(4, qt - 4 * s + 1);
    const int c_base = s * 256;

    for (int it = 0; it < n_it; ++it) {
        const int c0 = c_base + it * 64;
        __syncthreads();
#pragma unroll
        for (int j = 0; j < 2; ++j) {   // K tile: rows of q  ([hc][c] swizzled)
            int idx = t + j * 256;
            int c = idx >> 3, hc = idx & 7;
            Ks4[hc * 64 + (c ^ hc)] = *(const uint4*)(qb + (size_t)(c0 + c) * Hh + hc * 8);
        }
#pragma unroll
        for (int j = 0; j < 2; ++j) {   // V^T tile from qT  ([cc][h] swizzled)
            int idx = t + j * 256;
            int h = idx >> 3, cc = idx & 7;
            Vt4[cc * 64 + (h ^ cc)] = *(const uint4*)(qTb + (size_t)h * Ll + c0 + cc * 8);
        }
        __syncthreads();
        // S = Q . K^T  (rows w*16..+15 x cols 0..63)
        f32x4 sc[4];
#pragma unroll
        for (int ct = 0; ct < 4; ++ct) sc[ct] = (f32x4){0.f, 0.f, 0.f, 0.f};
#pragma unroll
        for (int ks = 0; ks < 2; ++ks) {
            int hc = ks * 4 + q_;
            s16x8 A = *(const s16x8*)&Qs4[hc * 64 + ((w * 16 + m15) ^ hc)];
#pragma unroll
            for (int ct = 0; ct < 4; ++ct) {
                s16x8 Bk = *(const s16x8*)&Ks4[hc * 64 + ((ct * 16 + m15) ^ hc)];
                sc[ct] = __builtin_amdgcn_mfma_f32_16x16x32_bf16(A, Bk, sc[ct], 0, 0, 0);
            }
        }
        const bool diag = (4 * s + it) == qt;
        // online softmax; lane owns rows q_*4+r (cols live across the 16 lanes of its quad)
#pragma unroll
        for (int r = 0; r < 4; ++r) {
            const int row = qt * 64 + w * 16 + q_ * 4 + r;
            float v[4];
#pragma unroll
            for (int ct = 0; ct < 4; ++ct) {
                float sv = sc[ct][r] * 0.03125f;
                if (diag && (c0 + ct * 16 + m15 > row)) sv = -INFINITY;
                v[ct] = sv;
            }
            float vmax = fmaxf(fmaxf(v[0], v[1]), fmaxf(v[2], v[3]));
            vmax = fmaxf(vmax, __shfl_xor(vmax, 1, 64));
            vmax = fmaxf(vmax, __shfl_xor(vmax, 2, 64));
            vmax = fmaxf(vmax, __shfl_xor(vmax, 4, 64));
            vmax = fmaxf(vmax, __shfl_xor(vmax, 8, 64));
            float mnew = fmaxf(mr[r], vmax);
            float alpha = __expf(mr[r] - mnew);      // first iter: exp(-inf)=0
            float psum = 0.f;
#pragma unroll
            for (int ct = 0; ct < 4; ++ct) {
                float p = __expf(v[ct] - mnew);
                psum += p;
                int c = ct * 16 + m15, cc = c >> 3;
                Pb[(w * 128 + cc * 16 + ((q_ * 4 + r) ^ cc)) * 8 + (c & 7)] = f2bf(p);
            }
            psum += __shfl_xor(psum, 1, 64);
            psum += __shfl_xor(psum, 2, 64);
            psum += __shfl_xor(psum, 4, 64);
            psum += __shfl_xor(psum, 8, 64);
            lr[r] = lr[r] * alpha + psum;
            mr[r] = mnew;
#pragma unroll
            for (int ht = 0; ht < 4; ++ht) Oacc[ht][r] *= alpha;
        }
        // O += P . V   (wave-private P in LDS -> A frags; no barrier: same-wave RAW)
#pragma unroll
        for (int ks = 0; ks < 2; ++ks) {
            int cc = ks * 4 + q_;
            s16x8 Ap = *(const s16x8*)&Pb[(w * 128 + cc * 16 + (m15 ^ cc)) * 8];
#pragma unroll
            for (int ht = 0; ht < 4; ++ht) {
                s16x8 Bv = *(const s16x8*)&Vt4[cc * 64 + ((ht * 16 + m15) ^ cc)];
                Oacc[ht] = __builtin_amdgcn_mfma_f32_16x16x32_bf16(Ap, Bv, Oacc[ht], 0, 0, 0);
            }
        }
    }
    // epilogue: unnormalized O partial + (m,l)
    const size_t base = ((size_t)((b * 32 + qt) * 8 + s)) * 4096;
#pragma unroll
    for (int ht = 0; ht < 4; ++ht)
#pragma unroll
        for (int r = 0; r < 4; ++r)
            PO[base + (size_t)(w * 16 + q_ * 4 + r) * 64 + ht * 16 + m15] = Oacc[ht][r];
    if (m15 == 0) {
        float* mlp = ML + ((size_t)((b * 32 + qt) * 8 + s)) * 128;
#pragma unroll
        for (int r = 0; r < 4; ++r) {
            mlp[(w * 16 + q_ * 4 + r) * 2 + 0] = mr[r];
            mlp[(w * 16 + q_ * 4 + r) * 2 + 1] = lr[r];
        }
    }
}

// ---------------- Kernel 3: combine slices ----------------
// grid (128, 2): (b,qt) x row-half; thread = 1 row x 8 cols.
__global__ __launch_bounds__(256) void combine_k(const float* __restrict__ PO,
                                                 const float* __restrict__ ML,
                                                 float* __restrict__ out) {
    const int bq = blockIdx.x;
    const int b = bq >> 5, qt = bq & 31;
    const int ns = (qt >> 2) + 1;
    const int t = threadIdx.x;
    const int r = blockIdx.y * 32 + (t >> 3);
    const int c8 = (t & 7) * 8;
    const float* mlp = ML + (size_t)bq * 8 * 128;
    const float* pob = PO + (size_t)bq * 8 * 4096;
    float M = -INFINITY;
    for (int si = 0; si < ns; ++si) M = fmaxf(M, mlp[si * 128 + r * 2]);
    float L = 0.f;
    f32x4 a0 = {0.f, 0.f, 0.f, 0.f}, a1 = a0;
    for (int si = 0; si < ns; ++si) {
        float ms = mlp[si * 128 + r * 2], ls = mlp[si * 128 + r * 2 + 1];
        float wgt = __expf(ms - M);
        L += ls * wgt;
        const f32x4* sp = (const f32x4*)(pob + (size_t)si * 4096 + r * 64 + c8);
        a0 += wgt * sp[0];
        a1 += wgt * sp[1];
    }
    float inv = 1.0f / L;
    f32x4* op = (f32x4*)(out + (size_t)(b * Ll + qt * 64 + r) * 64 + c8);
    op[0] = a0 * inv;
    op[1] = a1 * inv;
}

extern "C" void kernel_launch(void* const* d_in, const int* in_sizes, int n_in,
                              void* d_out, int out_size, void* d_ws, size_t ws_size,
                              hipStream_t stream) {
    const float* x  = (const float*)d_in[0];   // [4,2048,1024]
    const float* Wq = (const float*)d_in[1];   // [64,1024]
    float* out = (float*)d_out;                // [4,2048,64] fp32
    char* ws = (char*)d_ws;
    unsigned short* q  = (unsigned short*)ws;                 // 1 MB  bf16 [B*L][64]
    unsigned short* qT = (unsigned short*)(ws + (1 << 20));   // 1 MB  bf16 [B][64][L]
    float* PO = (float*)(ws + (2 << 20));                     // 16 MB partials
    float* ML = (float*)(ws + (18 << 20));                    // 512 KB (m,l)

    proj_mfma<<<512, 256, 0, stream>>>(x, Wq, q, qT);
    flash_mfma<<<dim3(32, 8, Bb), 256, 0, stream>>>(q, qT, PO, ML);
    combine_k<<<dim3(128, 2), 256, 0, stream>>>(PO, ML, out);
}

// Round 3
// 101.551 us; speedup vs baseline: 3.1488x; 1.1688x over previous
//
#include <hip/hip_runtime.h>
#include <cmath>

#define Bb 4
#define Ll 2048
#define Dd 1024
#define Hh 64

typedef float f32x4 __attribute__((ext_vector_type(4)));
typedef short s16x8 __attribute__((ext_vector_type(8)));

__device__ __forceinline__ unsigned short f2bf(float f) {
    union { float f; unsigned int u; } v; v.f = f;
    unsigned int u = v.u;
    return (unsigned short)((u + 0x7FFFu + ((u >> 16) & 1u)) >> 16);  // RNE
}
__device__ __forceinline__ unsigned int pack2(float a, float b) {
    return (unsigned int)f2bf(a) | ((unsigned int)f2bf(b) << 16);
}

// ---------------- Kernel 0: Wq fp32 -> bf16 (once) ----------------
__global__ __launch_bounds__(256) void wq_cvt(const float* __restrict__ Wq,
                                              unsigned short* __restrict__ wqb) {
    const int i = (blockIdx.x * 256 + threadIdx.x) * 8;
    float4 a = *(const float4*)(Wq + i);
    float4 b = *(const float4*)(Wq + i + 4);
    uint4 p; p.x = pack2(a.x, a.y); p.y = pack2(a.z, a.w);
    p.z = pack2(b.x, b.y); p.w = pack2(b.z, b.w);
    *(uint4*)(wqb + i) = p;
}

// ---------------- Kernel 1: q = x @ Wq^T, bf16 MFMA ----------------
// grid 512 (M=16 rows each), 256 threads, BK=256 (4 chunks). Wq staged as bf16 COPY.
// Wave w computes N-subtile nt=w (cols w*16..w*16+15). LDS 40 KB -> 2+ blocks/CU.
__global__ __launch_bounds__(256, 2) void proj_mfma(const float* __restrict__ x,
                                                    const unsigned short* __restrict__ wqb,
                                                    unsigned short* __restrict__ q,
                                                    unsigned short* __restrict__ qT) {
    __shared__ uint4 xs4[32 * 16];   // [kc 0..31][r ^ (kc&15)]  8 KB
    __shared__ uint4 ws4[32 * 64];   // [kc 0..31][h ^ kc]       32 KB
    const int t = threadIdx.x;
    const int lane = t & 63;
    const int w = t >> 6;
    const int m15 = lane & 15;
    const int q_ = lane >> 4;
    const int row0 = blockIdx.x * 16;

    f32x4 acc = {0.f, 0.f, 0.f, 0.f};

    for (int k0 = 0; k0 < Dd; k0 += 256) {
        __syncthreads();
#pragma unroll
        for (int j = 0; j < 2; ++j) {   // stage x[16][256] -> bf16
            int idx = t + j * 256;
            int r = idx >> 5, kc = idx & 31;
            const float* src = x + (size_t)(row0 + r) * Dd + k0 + kc * 8;
            float4 a = *(const float4*)src;
            float4 b = *(const float4*)(src + 4);
            uint4 p; p.x = pack2(a.x, a.y); p.y = pack2(a.z, a.w);
            p.z = pack2(b.x, b.y); p.w = pack2(b.z, b.w);
            xs4[kc * 16 + (r ^ (kc & 15))] = p;
        }
#pragma unroll
        for (int j = 0; j < 8; ++j) {   // stage Wq[64][256] bf16 (pure copy)
            int idx = t + j * 256;
            int h = idx >> 5, kc = idx & 31;
            ws4[kc * 64 + (h ^ kc)] = *(const uint4*)(wqb + (size_t)h * Dd + k0 + kc * 8);
        }
        __syncthreads();
#pragma unroll
        for (int ks = 0; ks < 8; ++ks) {
            int kc = ks * 4 + q_;
            s16x8 A = *(const s16x8*)&xs4[kc * 16 + (m15 ^ (kc & 15))];
            s16x8 B = *(const s16x8*)&ws4[kc * 64 + ((w * 16 + m15) ^ kc)];
            acc = __builtin_amdgcn_mfma_f32_16x16x32_bf16(A, B, acc, 0, 0, 0);
        }
    }
    // C layout: col=lane&15 -> h = w*16+m15 ; row = q_*4+reg
    const int h = w * 16 + m15;
    const int b = row0 >> 11;
    const int mloc = (row0 & 2047) + q_ * 4;
    unsigned short u0 = f2bf(acc[0]), u1 = f2bf(acc[1]), u2 = f2bf(acc[2]), u3 = f2bf(acc[3]);
    q[(size_t)(row0 + q_ * 4 + 0) * Hh + h] = u0;
    q[(size_t)(row0 + q_ * 4 + 1) * Hh + h] = u1;
    q[(size_t)(row0 + q_ * 4 + 2) * Hh + h] = u2;
    q[(size_t)(row0 + q_ * 4 + 3) * Hh + h] = u3;
    ushort4 pk; pk.x = u0; pk.y = u1; pk.z = u2; pk.w = u3;
    *(ushort4*)&qT[((size_t)(b * Hh + h)) * Ll + mloc] = pk;
}

// ---------------- Kernel 2: split-KV MFMA flash (S computed TRANSPOSED) ----------------
// grid (qt=32, slice=8, b=4); block 256 = 4 waves; wave w owns q-rows w*16..+15.
// S^T = K.Q^T : D tile ct -> lane(m15,q_) holds q-row m15, kv-cols ct*16+q_*4+reg.
// Softmax: in-lane over 16 regs + 2 shfl (q_ dim). O^T = V^T.P : D col = q-row.
__global__ __launch_bounds__(256, 3) void flash_mfma(const unsigned short* __restrict__ qg,
                                                     const unsigned short* __restrict__ qTg,
                                                     float* __restrict__ PO,
                                                     float* __restrict__ ML) {
    const int qt = blockIdx.x;
    const int s  = blockIdx.y;
    const int b  = blockIdx.z;
    if (s > (qt >> 2)) return;
    __shared__ uint4 Qs4[512], Ks4[512], Vt4[512];            // 8 KB each
    __shared__ __align__(16) unsigned short Pb[4 * 16 * 72];  // P rows, stride 72 bf16
    const int t = threadIdx.x, lane = t & 63, w = t >> 6;
    const int m15 = lane & 15, q_ = lane >> 4;
    const unsigned short* qb  = qg  + (size_t)b * Ll * Hh;
    const unsigned short* qTb = qTg + (size_t)b * Hh * Ll;

#pragma unroll
    for (int j = 0; j < 2; ++j) {   // stage Q tile rows qt*64..+63
        int idx = t + j * 256;
        int r = idx >> 3, hc = idx & 7;
        Qs4[hc * 64 + (r ^ hc)] = *(const uint4*)(qb + (size_t)(qt * 64 + r) * Hh + hc * 8);
    }
    f32x4 Oacc[4];
#pragma unroll
    for (int i = 0; i < 4; ++i) Oacc[i] = (f32x4){0.f, 0.f, 0.f, 0.f};
    float mr = -INFINITY, lr = 0.f;
    const int n_it = min(4, qt - 4 * s + 1);
    const int c_base = s * 256;
    const int row = qt * 64 + w * 16 + m15;            // this lane's q-row
    unsigned short* Pr = Pb + (w * 16 + m15) * 72;     // this lane's P row (wave-private)

    for (int it = 0; it < n_it; ++it) {
        const int c0 = c_base + it * 64;
        __syncthreads();
#pragma unroll
        for (int j = 0; j < 2; ++j) {   // K tile
            int idx = t + j * 256;
            int c = idx >> 3, hc = idx & 7;
            Ks4[hc * 64 + (c ^ hc)] = *(const uint4*)(qb + (size_t)(c0 + c) * Hh + hc * 8);
        }
#pragma unroll
        for (int j = 0; j < 2; ++j) {   // V^T tile
            int idx = t + j * 256;
            int h = idx >> 3, cc = idx & 7;
            Vt4[cc * 64 + (h ^ cc)] = *(const uint4*)(qTb + (size_t)h * Ll + c0 + cc * 8);
        }
        __syncthreads();
        // S^T tiles: A = K frag (m=kv), B = Q frag (n=q-row)
        f32x4 sc[4];
#pragma unroll
        for (int ct = 0; ct < 4; ++ct) sc[ct] = (f32x4){0.f, 0.f, 0.f, 0.f};
#pragma unroll
        for (int ks = 0; ks < 2; ++ks) {
            int hc = ks * 4 + q_;
            s16x8 Bq = *(const s16x8*)&Qs4[hc * 64 + ((w * 16 + m15) ^ hc)];
#pragma unroll
            for (int ct = 0; ct < 4; ++ct) {
                s16x8 Ak = *(const s16x8*)&Ks4[hc * 64 + ((ct * 16 + m15) ^ hc)];
                sc[ct] = __builtin_amdgcn_mfma_f32_16x16x32_bf16(Ak, Bq, sc[ct], 0, 0, 0);
            }
        }
        const bool diag = (4 * s + it) == qt;
        // masked scores for this q-row: kv-col = c0 + ct*16 + q_*4 + reg
        float v[16];
#pragma unroll
        for (int ct = 0; ct < 4; ++ct)
#pragma unroll
            for (int r = 0; r < 4; ++r) {
                float sv = sc[ct][r] * 0.03125f;
                if (diag && (c0 + ct * 16 + q_ * 4 + r > row)) sv = -INFINITY;
                v[ct * 4 + r] = sv;
            }
        float vmax = v[0];
#pragma unroll
        for (int i = 1; i < 16; ++i) vmax = fmaxf(vmax, v[i]);
        vmax = fmaxf(vmax, __shfl_xor(vmax, 16, 64));
        vmax = fmaxf(vmax, __shfl_xor(vmax, 32, 64));
        float mnew = fmaxf(mr, vmax);
        float alpha = __expf(mr - mnew);               // first iter: exp(-inf)=0
        float p[16];
        float psum = 0.f;
#pragma unroll
        for (int i = 0; i < 16; ++i) { p[i] = __expf(v[i] - mnew); psum += p[i]; }
        psum += __shfl_xor(psum, 16, 64);
        psum += __shfl_xor(psum, 32, 64);
        lr = lr * alpha + psum;
        mr = mnew;
#pragma unroll
        for (int ht = 0; ht < 4; ++ht) Oacc[ht] *= alpha;
        // write P row (bf16, packed pairs): kv slot ct*16 + q_*4, 8 bytes per ct
#pragma unroll
        for (int ct = 0; ct < 4; ++ct) {
            uint2 pr; pr.x = pack2(p[ct * 4 + 0], p[ct * 4 + 1]);
            pr.y = pack2(p[ct * 4 + 2], p[ct * 4 + 3]);
            *(uint2*)(Pr + ct * 16 + q_ * 4) = pr;     // same-wave RAW, no barrier
        }
        // O^T += V^T . P : A = V^T frag (m=h), B = own P row chunk (n=q-row)
#pragma unroll
        for (int kc = 0; kc < 2; ++kc) {
            int cc = kc * 4 + q_;
            s16x8 Bp = *(const s16x8*)(Pr + kc * 32 + q_ * 8);
#pragma unroll
            for (int ht = 0; ht < 4; ++ht) {
                s16x8 Av = *(const s16x8*)&Vt4[cc * 64 + ((ht * 16 + m15) ^ cc)];
                Oacc[ht] = __builtin_amdgcn_mfma_f32_16x16x32_bf16(Av, Bp, Oacc[ht], 0, 0, 0);
            }
        }
    }
    // epilogue: D col = q-row (m15), row = h-local = q_*4+reg -> h-contiguous float4
    const size_t base = ((size_t)((b * 32 + qt) * 8 + s)) * 4096;
#pragma unroll
    for (int ht = 0; ht < 4; ++ht)
        *(f32x4*)&PO[base + (size_t)(w * 16 + m15) * 64 + ht * 16 + q_ * 4] = Oacc[ht];
    if (q_ == 0) {
        float* mlp = ML + ((size_t)((b * 32 + qt) * 8 + s)) * 128;
        mlp[(w * 16 + m15) * 2 + 0] = mr;
        mlp[(w * 16 + m15) * 2 + 1] = lr;
    }
}

// ---------------- Kernel 3: combine slices ----------------
__global__ __launch_bounds__(256) void combine_k(const float* __restrict__ PO,
                                                 const float* __restrict__ ML,
                                                 float* __restrict__ out) {
    const int bq = blockIdx.x;
    const int b = bq >> 5, qt = bq & 31;
    const int ns = (qt >> 2) + 1;
    const int t = threadIdx.x;
    const int r = blockIdx.y * 32 + (t >> 3);
    const int c8 = (t & 7) * 8;
    const float* mlp = ML + (size_t)bq * 8 * 128;
    const float* pob = PO + (size_t)bq * 8 * 4096;
    float M = -INFINITY;
    for (int si = 0; si < ns; ++si) M = fmaxf(M, mlp[si * 128 + r * 2]);
    float L = 0.f;
    f32x4 a0 = {0.f, 0.f, 0.f, 0.f}, a1 = a0;
    for (int si = 0; si < ns; ++si) {
        float ms = mlp[si * 128 + r * 2], ls = mlp[si * 128 + r * 2 + 1];
        float wgt = __expf(ms - M);
        L += ls * wgt;
        const f32x4* sp = (const f32x4*)(pob + (size_t)si * 4096 + r * 64 + c8);
        a0 += wgt * sp[0];
        a1 += wgt * sp[1];
    }
    float inv = 1.0f / L;
    f32x4* op = (f32x4*)(out + (size_t)(b * Ll + qt * 64 + r) * 64 + c8);
    op[0] = a0 * inv;
    op[1] = a1 * inv;
}

extern "C" void kernel_launch(void* const* d_in, const int* in_sizes, int n_in,
                              void* d_out, int out_size, void* d_ws, size_t ws_size,
                              hipStream_t stream) {
    const float* x  = (const float*)d_in[0];   // [4,2048,1024]
    const float* Wq = (const float*)d_in[1];   // [64,1024]
    float* out = (float*)d_out;                // [4,2048,64] fp32
    char* ws = (char*)d_ws;
    unsigned short* q   = (unsigned short*)ws;                 // 1 MB  bf16 [B*L][64]
    unsigned short* qT  = (unsigned short*)(ws + (1 << 20));   // 1 MB  bf16 [B][64][L]
    float* PO = (float*)(ws + (2 << 20));                      // 16 MB partials
    float* ML = (float*)(ws + (18 << 20));                     // 512 KB (m,l)
    unsigned short* wqb = (unsigned short*)(ws + (19 << 20));  // 128 KB Wq bf16

    wq_cvt<<<32, 256, 0, stream>>>(Wq, wqb);
    proj_mfma<<<512, 256, 0, stream>>>(x, wqb, q, qT);
    flash_mfma<<<dim3(32, 8, Bb), 256, 0, stream>>>(q, qT, PO, ML);
    combine_k<<<dim3(128, 2), 256, 0, stream>>>(PO, ML, out);
}